// Round 6
// baseline (298.348 us; speedup 1.0000x reference)
//
#include <hip/hip_runtime.h>
#include <hip/hip_bf16.h>

#define WDIM 192
#define PLANE (192 * 192)
#define VOL (192 * 192 * 192)
#define HC 12          // h-rows produced per block in wh_pass
#define TR (HC + 8)    // tile rows incl. halo = 20
#define ROWW 200       // padded LDS row: 4 zero cols each side
#define DC 12          // d-slices per block in d_pass

__global__ void zero_out_k(float* out) { out[0] = 0.0f; }

// pack two floats -> one uint holding 2 bf16 (RN), lo = a, hi = b
static __device__ inline unsigned int pk_bf16(float a, float b) {
    union { __hip_bfloat162 v; unsigned int u; } cvt;
    cvt.v = __float22bfloat162_rn(make_float2(a, b));
    return cvt.u;
}
static __device__ inline float bf_lo(unsigned int u) {
    union { unsigned int u; float f; } c; c.u = u << 16; return c.f;
}
static __device__ inline float bf_hi(unsigned int u) {
    union { unsigned int u; float f; } c; c.u = u & 0xffff0000u; return c.f;
}

// --- Pass 1: fused W-box + H-box sums -> packed bf16x8 per voxel -----------
// LDS: one padded bf16-pair array, 20x200x4 = 16 KB -> 10 blocks/CU.
__global__ __launch_bounds__(192) void wh_pass(const float* __restrict__ I,
                                               const float* __restrict__ J,
                                               uint4* __restrict__ B) {
    __shared__ unsigned int sPK[TR * ROWW];   // 16000 B
    const int t = threadIdx.x;           // w
    const int d = blockIdx.x >> 4;
    const int c = blockIdx.x & 15;
    const int h0 = c * HC;

    const size_t dbase = (size_t)d * PLANE;

    // zero the 8 pad columns of each row (TR*8 = 160 entries)
    if (t < TR * 8) {
        const int row = t >> 3;
        const int p = t & 7;
        const int col = (p < 4) ? p : (192 + p);
        sPK[row * ROWW + col] = 0u;
    }

    // cooperative staging: rows 0..19, cols 0..191 (+4 offset in LDS)
    // TR*WDIM/4 = 960 float4 groups; 5 per thread.
    #pragma unroll
    for (int i = 0; i < 5; ++i) {
        const int idx4 = i * 192 + t;        // 0..959
        const int row  = idx4 / 48;          // 0..19
        const int col4 = (idx4 - row * 48) * 4;
        const int h = h0 - 4 + row;
        float4 vI = make_float4(0.f, 0.f, 0.f, 0.f);
        float4 vJ = vI;
        if (h >= 0 && h < WDIM) {
            vI = *(const float4*)(I + dbase + (size_t)h * WDIM + col4);
            vJ = *(const float4*)(J + dbase + (size_t)h * WDIM + col4);
        }
        uint4 u;
        u.x = pk_bf16(vI.x, vJ.x);
        u.y = pk_bf16(vI.y, vJ.y);
        u.z = pk_bf16(vI.z, vJ.z);
        u.w = pk_bf16(vI.w, vJ.w);
        *(uint4*)&sPK[row * ROWW + 4 + col4] = u;   // 16B-aligned
    }
    __syncthreads();

    float ring0[9], ring1[9], ring2[9], ring3[9], ring4[9];
    #pragma unroll
    for (int j = 0; j < 9; ++j) { ring0[j]=0.f; ring1[j]=0.f; ring2[j]=0.f; ring3[j]=0.f; ring4[j]=0.f; }
    float s0 = 0.f, s1 = 0.f, s2 = 0.f, s3 = 0.f, s4 = 0.f;

    // steps s = 0..TR-1; emit h_out = h0 + s - 8 for s >= 8
    #pragma unroll
    for (int o = 0; o < 3; ++o) {
        #pragma unroll
        for (int j = 0; j < 9; ++j) {
            const int s = o * 9 + j;
            if (s < TR) {
                const unsigned int* rowp = &sPK[s * ROWW + t]; // k=0..8 -> w=t-4+k
                float w0 = 0.f, w1 = 0.f, w2 = 0.f, w3 = 0.f, w4 = 0.f;
                #pragma unroll
                for (int k = 0; k < 9; ++k) {
                    const unsigned int u = rowp[k];
                    const float a = bf_lo(u);
                    const float b = bf_hi(u);
                    w0 += a; w1 += b;
                    w2 += a * a; w3 += b * b; w4 += a * b;
                }
                s0 += w0 - ring0[j]; ring0[j] = w0;
                s1 += w1 - ring1[j]; ring1[j] = w1;
                s2 += w2 - ring2[j]; ring2[j] = w2;
                s3 += w3 - ring3[j]; ring3[j] = w3;
                s4 += w4 - ring4[j]; ring4[j] = w4;

                if (s >= 8) {
                    const int h_out = h0 + s - 8;
                    const unsigned int cu = sPK[(s - 4) * ROWW + t + 4];
                    const float ci = bf_lo(cu);
                    const float cj = bf_hi(cu);
                    uint4 q;
                    q.x = pk_bf16(s0, s1);
                    q.y = pk_bf16(s2, s3);
                    q.z = pk_bf16(s4, ci);
                    q.w = pk_bf16(cj, 0.f);
                    B[dbase + (size_t)h_out * WDIM + t] = q;
                }
            }
        }
    }
}

// --- Pass 2: D-axis sliding box sum + NCC + reduction ----------------------
// Per o-group: batch-issue 9 guarded uint4 loads, then process.
__global__ __launch_bounds__(192) void d_pass(const uint4* __restrict__ B,
                                              float* __restrict__ out) {
    const int t = threadIdx.x;
    const int h = blockIdx.x >> 4;
    const int c = blockIdx.x & 15;
    const int d0 = c * DC;
    const int base_h = h * WDIM + t;

    float r0[9], r1[9], r2[9], r3[9], r4[9], rI[9], rJ[9];
    #pragma unroll
    for (int j = 0; j < 9; ++j) { r0[j]=0.f; r1[j]=0.f; r2[j]=0.f; r3[j]=0.f; r4[j]=0.f; rI[j]=0.f; rJ[j]=0.f; }
    float s0 = 0.f, s1 = 0.f, s2 = 0.f, s3 = 0.f, s4 = 0.f;

    const float inv_k = 1.0f / 729.0f;
    float local = 0.f;

    // steps s = 0..DC+7 : d_in = d0-4+s ; emit d_out = d_in-4 for s >= 8
    #pragma unroll
    for (int o = 0; o < 3; ++o) {
        uint4 q[9];
        #pragma unroll
        for (int j = 0; j < 9; ++j) {
            const int s = o * 9 + j;
            const int d_in = d0 - 4 + s;
            q[j] = make_uint4(0u, 0u, 0u, 0u);
            if (s < DC + 8 && d_in >= 0 && d_in < WDIM)
                q[j] = B[(size_t)d_in * PLANE + base_h];
        }
        #pragma unroll
        for (int j = 0; j < 9; ++j) {
            const int s = o * 9 + j;
            if (s < DC + 8) {
                const float f0 = bf_lo(q[j].x), f1 = bf_hi(q[j].x);
                const float f2 = bf_lo(q[j].y), f3 = bf_hi(q[j].y);
                const float f4 = bf_lo(q[j].z), f5 = bf_hi(q[j].z);
                const float f6 = bf_lo(q[j].w);
                s0 += f0 - r0[j]; r0[j] = f0;
                s1 += f1 - r1[j]; r1[j] = f1;
                s2 += f2 - r2[j]; r2[j] = f2;
                s3 += f3 - r3[j]; r3[j] = f3;
                s4 += f4 - r4[j]; r4[j] = f4;
                rI[j] = f5; rJ[j] = f6;

                if (s >= 8) {
                    const float vi = rI[(j + 5) % 9];   // staged 4 steps ago
                    const float vj = rJ[(j + 5) % 9];
                    const float Iu = vi * inv_k;
                    const float Ju = vj * inv_k;
                    const float cross = s4 - s0 * Ju - s1 * Iu + Iu * Ju * 729.0f;
                    const float Ivar  = s2 - 2.0f * s0 * Iu + Iu * Iu * 729.0f;
                    const float Jvar  = s3 - 2.0f * s1 * Ju + Ju * Ju * 729.0f;
                    local += (cross * cross) / (Ivar * Jvar + 1e-5f);
                }
            }
        }
    }

    __shared__ float sred[192];
    sred[t] = local;
    __syncthreads();
    if (t < 64) {
        float v = sred[t] + sred[t + 64] + sred[t + 128];
        #pragma unroll
        for (int off = 32; off; off >>= 1) v += __shfl_down(v, off);
        if (t == 0) {
            atomicAdd(out, v * (-1.0f / 14155776.0f));
        }
    }
}

extern "C" void kernel_launch(void* const* d_in, const int* in_sizes, int n_in,
                              void* d_out, int out_size, void* d_ws, size_t ws_size,
                              hipStream_t stream) {
    const float* I = (const float*)d_in[0];
    const float* J = (const float*)d_in[1];
    float* out = (float*)d_out;

    // Workspace: packed bf16x8 HW-summed volume, reused per batch: 113.2 MB.
    uint4* B = (uint4*)d_ws;

    zero_out_k<<<1, 1, 0, stream>>>(out);

    for (int b = 0; b < 2; ++b) {
        const float* Ib = I + (size_t)b * VOL;
        const float* Jb = J + (size_t)b * VOL;
        wh_pass<<<192 * 16, 192, 0, stream>>>(Ib, Jb, B);
        d_pass<<<192 * 16, 192, 0, stream>>>(B, out);
    }
}

// Round 7
// 264.356 us; speedup vs baseline: 1.1286x; 1.1286x over previous
//
#include <hip/hip_runtime.h>
#include <hip/hip_bf16.h>

#define WDIM 192
#define PLANE (192 * 192)
#define VOL (192 * 192 * 192)
#define HC 24          // h-rows produced per block in wh_pass
#define TR (HC + 8)    // tile rows incl. halo = 32
#define ROWW 200       // padded LDS row: 4 zero cols each side
#define DC 24          // d-slices per block in d_pass

__global__ void zero_out_k(float* out) { out[0] = 0.0f; }

// pack two floats -> one uint holding 2 bf16 (RN), lo = a, hi = b
static __device__ inline unsigned int pk_bf16(float a, float b) {
    union { __hip_bfloat162 v; unsigned int u; } cvt;
    cvt.v = __float22bfloat162_rn(make_float2(a, b));
    return cvt.u;
}
static __device__ inline float bf_lo(unsigned int u) {
    union { unsigned int u; float f; } c; c.u = u << 16; return c.f;
}
static __device__ inline float bf_hi(unsigned int u) {
    union { unsigned int u; float f; } c; c.u = u & 0xffff0000u; return c.f;
}

// --- Pass 1: fused W-box + H-box sums -> packed bf16x8 per voxel -----------
// LDS: padded bf16-pair tile 32x200x4 = 25.6 KB.
// Tap pipeline: prefetch row s+1's 9 taps while processing row s.
__global__ __launch_bounds__(192) void wh_pass(const float* __restrict__ I,
                                               const float* __restrict__ J,
                                               uint4* __restrict__ B) {
    __shared__ unsigned int sPK[TR * ROWW];   // 25600 B
    const int t = threadIdx.x;           // w
    const int d = blockIdx.x >> 3;
    const int c = blockIdx.x & 7;
    const int h0 = c * HC;

    const size_t dbase = (size_t)d * PLANE;

    // zero the 8 pad columns of each row (TR*8 = 256 entries)
    {
        const int i0 = t;
        if (i0 < 256) {
            const int row = i0 >> 3;
            const int p = i0 & 7;
            const int col = (p < 4) ? p : (192 + p);
            sPK[row * ROWW + col] = 0u;
        }
        const int i1 = t + 192;
        if (i1 < 256) {
            const int row = i1 >> 3;
            const int p = i1 & 7;
            const int col = (p < 4) ? p : (192 + p);
            sPK[row * ROWW + col] = 0u;
        }
    }

    // cooperative staging: rows 0..31, cols 0..191 (+4 offset in LDS)
    #pragma unroll
    for (int i = 0; i < 8; ++i) {
        const int idx4 = i * 192 + t;        // 0..1535
        const int row  = idx4 / 48;          // 0..31
        const int col4 = (idx4 - row * 48) * 4;
        const int h = h0 - 4 + row;
        float4 vI = make_float4(0.f, 0.f, 0.f, 0.f);
        float4 vJ = vI;
        if (h >= 0 && h < WDIM) {
            vI = *(const float4*)(I + dbase + (size_t)h * WDIM + col4);
            vJ = *(const float4*)(J + dbase + (size_t)h * WDIM + col4);
        }
        uint4 u;
        u.x = pk_bf16(vI.x, vJ.x);
        u.y = pk_bf16(vI.y, vJ.y);
        u.z = pk_bf16(vI.z, vJ.z);
        u.w = pk_bf16(vI.w, vJ.w);
        *(uint4*)&sPK[row * ROWW + 4 + col4] = u;   // 16B-aligned
    }
    __syncthreads();

    float ring0[9], ring1[9], ring2[9], ring3[9], ring4[9];
    #pragma unroll
    for (int j = 0; j < 9; ++j) { ring0[j]=0.f; ring1[j]=0.f; ring2[j]=0.f; ring3[j]=0.f; ring4[j]=0.f; }
    float s0 = 0.f, s1 = 0.f, s2 = 0.f, s3 = 0.f, s4 = 0.f;

    unsigned int uA[9], uB[9];
    // preload taps of row 0
    #pragma unroll
    for (int k = 0; k < 9; ++k) uA[k] = sPK[0 * ROWW + t + k];

    // 32 steps exactly; ring index = s % 9 (compile-time); ping-pong uA/uB
    #pragma unroll
    for (int s = 0; s < TR; ++s) {
        // prefetch row s+1 into the idle buffer
        if (s + 1 < TR) {
            if ((s & 1) == 0) {
                #pragma unroll
                for (int k = 0; k < 9; ++k) uB[k] = sPK[(s + 1) * ROWW + t + k];
            } else {
                #pragma unroll
                for (int k = 0; k < 9; ++k) uA[k] = sPK[(s + 1) * ROWW + t + k];
            }
        }
        float w0 = 0.f, w1 = 0.f, w2 = 0.f, w3 = 0.f, w4 = 0.f;
        #pragma unroll
        for (int k = 0; k < 9; ++k) {
            const unsigned int u = ((s & 1) == 0) ? uA[k] : uB[k];
            const float a = bf_lo(u);
            const float b = bf_hi(u);
            w0 += a; w1 += b;
            w2 += a * a; w3 += b * b; w4 += a * b;
        }
        const int j = s % 9;
        s0 += w0 - ring0[j]; ring0[j] = w0;
        s1 += w1 - ring1[j]; ring1[j] = w1;
        s2 += w2 - ring2[j]; ring2[j] = w2;
        s3 += w3 - ring3[j]; ring3[j] = w3;
        s4 += w4 - ring4[j]; ring4[j] = w4;

        if (s >= 8) {
            const int h_out = h0 + s - 8;
            const unsigned int cu = sPK[(s - 4) * ROWW + t + 4];
            const float ci = bf_lo(cu);
            const float cj = bf_hi(cu);
            uint4 q;
            q.x = pk_bf16(s0, s1);
            q.y = pk_bf16(s2, s3);
            q.z = pk_bf16(s4, ci);
            q.w = pk_bf16(cj, 0.f);
            B[dbase + (size_t)h_out * WDIM + t] = q;
        }
    }
}

// --- Pass 2: D-axis sliding box sum + NCC + reduction ----------------------
// 32 steps in 4 groups of 8; issue group g+1's loads before processing g.
__global__ __launch_bounds__(192) void d_pass(const uint4* __restrict__ B,
                                              float* __restrict__ out) {
    const int t = threadIdx.x;
    const int h = blockIdx.x >> 3;
    const int c = blockIdx.x & 7;
    const int d0 = c * DC;
    const int base_h = h * WDIM + t;

    float r0[9], r1[9], r2[9], r3[9], r4[9], rI[9], rJ[9];
    #pragma unroll
    for (int j = 0; j < 9; ++j) { r0[j]=0.f; r1[j]=0.f; r2[j]=0.f; r3[j]=0.f; r4[j]=0.f; rI[j]=0.f; rJ[j]=0.f; }
    float s0 = 0.f, s1 = 0.f, s2 = 0.f, s3 = 0.f, s4 = 0.f;

    const float inv_k = 1.0f / 729.0f;
    float local = 0.f;

    uint4 qA[8], qB[8];
    // preload group 0 (steps 0..7, d_in = d0-4 .. d0+3)
    #pragma unroll
    for (int i = 0; i < 8; ++i) {
        const int d_in = d0 - 4 + i;
        qA[i] = make_uint4(0u, 0u, 0u, 0u);
        if (d_in >= 0 && d_in < WDIM)
            qA[i] = B[(size_t)d_in * PLANE + base_h];
    }

    #pragma unroll
    for (int g = 0; g < 4; ++g) {
        // issue group g+1's loads into the idle buffer
        if (g + 1 < 4) {
            #pragma unroll
            for (int i = 0; i < 8; ++i) {
                const int s = (g + 1) * 8 + i;
                const int d_in = d0 - 4 + s;
                uint4 v = make_uint4(0u, 0u, 0u, 0u);
                if (d_in >= 0 && d_in < WDIM)
                    v = B[(size_t)d_in * PLANE + base_h];
                if ((g & 1) == 0) qB[i] = v; else qA[i] = v;
            }
        }
        // process group g
        #pragma unroll
        for (int i = 0; i < 8; ++i) {
            const int s = g * 8 + i;
            const uint4 q = ((g & 1) == 0) ? qA[i] : qB[i];
            const float f0 = bf_lo(q.x), f1 = bf_hi(q.x);
            const float f2 = bf_lo(q.y), f3 = bf_hi(q.y);
            const float f4 = bf_lo(q.z), f5 = bf_hi(q.z);
            const float f6 = bf_lo(q.w);
            const int j = s % 9;
            s0 += f0 - r0[j]; r0[j] = f0;
            s1 += f1 - r1[j]; r1[j] = f1;
            s2 += f2 - r2[j]; r2[j] = f2;
            s3 += f3 - r3[j]; r3[j] = f3;
            s4 += f4 - r4[j]; r4[j] = f4;
            rI[j] = f5; rJ[j] = f6;

            if (s >= 8) {
                const int jc = (s - 4) % 9;      // center staged 4 steps ago
                const float vi = rI[jc];
                const float vj = rJ[jc];
                const float Iu = vi * inv_k;
                const float Ju = vj * inv_k;
                const float cross = s4 - s0 * Ju - s1 * Iu + Iu * Ju * 729.0f;
                const float Ivar  = s2 - 2.0f * s0 * Iu + Iu * Iu * 729.0f;
                const float Jvar  = s3 - 2.0f * s1 * Ju + Ju * Ju * 729.0f;
                local += (cross * cross) / (Ivar * Jvar + 1e-5f);
            }
        }
    }

    __shared__ float sred[192];
    sred[t] = local;
    __syncthreads();
    if (t < 64) {
        float v = sred[t] + sred[t + 64] + sred[t + 128];
        #pragma unroll
        for (int off = 32; off; off >>= 1) v += __shfl_down(v, off);
        if (t == 0) {
            atomicAdd(out, v * (-1.0f / 14155776.0f));
        }
    }
}

extern "C" void kernel_launch(void* const* d_in, const int* in_sizes, int n_in,
                              void* d_out, int out_size, void* d_ws, size_t ws_size,
                              hipStream_t stream) {
    const float* I = (const float*)d_in[0];
    const float* J = (const float*)d_in[1];
    float* out = (float*)d_out;

    // Workspace: packed bf16x8 HW-summed volume, reused per batch: 113.2 MB.
    uint4* B = (uint4*)d_ws;

    zero_out_k<<<1, 1, 0, stream>>>(out);

    for (int b = 0; b < 2; ++b) {
        const float* Ib = I + (size_t)b * VOL;
        const float* Jb = J + (size_t)b * VOL;
        wh_pass<<<192 * 8, 192, 0, stream>>>(Ib, Jb, B);
        d_pass<<<192 * 8, 192, 0, stream>>>(B, out);
    }
}

// Round 8
// 246.279 us; speedup vs baseline: 1.2114x; 1.0734x over previous
//
#include <hip/hip_runtime.h>
#include <hip/hip_bf16.h>

#define WDIM 192
#define PLANE (192 * 192)
#define VOL (192 * 192 * 192)
#define HC 24          // h-rows produced per block in wh_pass
#define TR (HC + 8)    // tile rows incl. halo = 32
#define ROWW 200       // padded LDS row: 4 zero cols each side
#define DC 24          // d-slices per block in d_pass

__global__ void zero_out_k(float* out) { out[0] = 0.0f; }

// pack two floats -> one uint holding 2 bf16 (RN), lo = a, hi = b
static __device__ inline unsigned int pk_bf16(float a, float b) {
    union { __hip_bfloat162 v; unsigned int u; } cvt;
    cvt.v = __float22bfloat162_rn(make_float2(a, b));
    return cvt.u;
}
static __device__ inline float bf_lo(unsigned int u) {
    union { unsigned int u; float f; } c; c.u = u << 16; return c.f;
}
static __device__ inline float bf_hi(unsigned int u) {
    union { unsigned int u; float f; } c; c.u = u & 0xffff0000u; return c.f;
}

// --- Pass 1: fused W-box + H-box sums -> 12-byte records (5 bf16 sums) -----
// grid (1536, nb): x = d*8 + h_chunk, y = batch.
__global__ __launch_bounds__(192) void wh_pass(const float* __restrict__ I,
                                               const float* __restrict__ J,
                                               unsigned int* __restrict__ B) {
    __shared__ unsigned int sPK[TR * ROWW];   // 25600 B
    const int t = threadIdx.x;           // w
    const int d = blockIdx.x >> 3;
    const int c = blockIdx.x & 7;
    const int h0 = c * HC;

    const size_t bofs = (size_t)blockIdx.y * VOL;
    const float* Ib = I + bofs;
    const float* Jb = J + bofs;
    unsigned int* Bb = B + bofs * 3;

    const size_t dbase = (size_t)d * PLANE;

    // zero the 8 pad columns of each row (TR*8 = 256 entries)
    {
        if (t < 256 - 192) { // t+192 path
            const int i1 = t + 192;
            const int row = i1 >> 3;
            const int p = i1 & 7;
            const int col = (p < 4) ? p : (192 + p);
            sPK[row * ROWW + col] = 0u;
        }
        const int row = t >> 3;
        const int p = t & 7;
        const int col = (p < 4) ? p : (192 + p);
        if (t < 256) sPK[row * ROWW + col] = 0u;
    }

    // cooperative staging: rows 0..31, cols 0..191 (+4 offset in LDS)
    #pragma unroll
    for (int i = 0; i < 8; ++i) {
        const int idx4 = i * 192 + t;        // 0..1535
        const int row  = idx4 / 48;          // 0..31
        const int col4 = (idx4 - row * 48) * 4;
        const int h = h0 - 4 + row;
        float4 vI = make_float4(0.f, 0.f, 0.f, 0.f);
        float4 vJ = vI;
        if (h >= 0 && h < WDIM) {
            vI = *(const float4*)(Ib + dbase + (size_t)h * WDIM + col4);
            vJ = *(const float4*)(Jb + dbase + (size_t)h * WDIM + col4);
        }
        uint4 u;
        u.x = pk_bf16(vI.x, vJ.x);
        u.y = pk_bf16(vI.y, vJ.y);
        u.z = pk_bf16(vI.z, vJ.z);
        u.w = pk_bf16(vI.w, vJ.w);
        *(uint4*)&sPK[row * ROWW + 4 + col4] = u;   // 16B-aligned
    }
    __syncthreads();

    float ring0[9], ring1[9], ring2[9], ring3[9], ring4[9];
    #pragma unroll
    for (int j = 0; j < 9; ++j) { ring0[j]=0.f; ring1[j]=0.f; ring2[j]=0.f; ring3[j]=0.f; ring4[j]=0.f; }
    float s0 = 0.f, s1 = 0.f, s2 = 0.f, s3 = 0.f, s4 = 0.f;

    unsigned int uA[9], uB[9];
    #pragma unroll
    for (int k = 0; k < 9; ++k) uA[k] = sPK[0 * ROWW + t + k];

    #pragma unroll
    for (int s = 0; s < TR; ++s) {
        if (s + 1 < TR) {
            if ((s & 1) == 0) {
                #pragma unroll
                for (int k = 0; k < 9; ++k) uB[k] = sPK[(s + 1) * ROWW + t + k];
            } else {
                #pragma unroll
                for (int k = 0; k < 9; ++k) uA[k] = sPK[(s + 1) * ROWW + t + k];
            }
        }
        float w0 = 0.f, w1 = 0.f, w2 = 0.f, w3 = 0.f, w4 = 0.f;
        #pragma unroll
        for (int k = 0; k < 9; ++k) {
            const unsigned int u = ((s & 1) == 0) ? uA[k] : uB[k];
            const float a = bf_lo(u);
            const float b = bf_hi(u);
            w0 += a; w1 += b;
            w2 += a * a; w3 += b * b; w4 += a * b;
        }
        const int j = s % 9;
        s0 += w0 - ring0[j]; ring0[j] = w0;
        s1 += w1 - ring1[j]; ring1[j] = w1;
        s2 += w2 - ring2[j]; ring2[j] = w2;
        s3 += w3 - ring3[j]; ring3[j] = w3;
        s4 += w4 - ring4[j]; ring4[j] = w4;

        if (s >= 8) {
            const int h_out = h0 + s - 8;
            const size_t idx = dbase + (size_t)h_out * WDIM + t;
            uint3 q;
            q.x = pk_bf16(s0, s1);
            q.y = pk_bf16(s2, s3);
            q.z = pk_bf16(s4, 0.f);
            *(uint3*)(Bb + idx * 3) = q;
        }
    }
}

// --- Pass 2: D-axis sliding box sum + NCC + reduction ----------------------
// 12-byte records; centers re-read from fp32 I,J (L3-served).
// 32 steps in 4 groups of 8; prefetch group g+1 (records + centers) before
// processing group g.
__global__ __launch_bounds__(192) void d_pass(const unsigned int* __restrict__ B,
                                              const float* __restrict__ I,
                                              const float* __restrict__ J,
                                              float* __restrict__ out) {
    const int t = threadIdx.x;
    const int h = blockIdx.x >> 3;
    const int c = blockIdx.x & 7;
    const int d0 = c * DC;
    const int base_h = h * WDIM + t;

    const size_t bofs = (size_t)blockIdx.y * VOL;
    const float* Ib = I + bofs;
    const float* Jb = J + bofs;
    const unsigned int* Bb = B + bofs * 3;

    float r0[9], r1[9], r2[9], r3[9], r4[9];
    #pragma unroll
    for (int j = 0; j < 9; ++j) { r0[j]=0.f; r1[j]=0.f; r2[j]=0.f; r3[j]=0.f; r4[j]=0.f; }
    float s0 = 0.f, s1 = 0.f, s2 = 0.f, s3 = 0.f, s4 = 0.f;

    const float inv_k = 1.0f / 729.0f;
    float local = 0.f;

    uint3 qA[8], qB[8];
    float2 cA[8], cB[8];
    // preload group 0 records (steps 0..7, d_in = d0-4 .. d0+3); no outputs yet
    #pragma unroll
    for (int i = 0; i < 8; ++i) {
        const int d_in = d0 - 4 + i;
        qA[i] = make_uint3(0u, 0u, 0u);
        if (d_in >= 0 && d_in < WDIM)
            qA[i] = *(const uint3*)(Bb + ((size_t)d_in * PLANE + base_h) * 3);
        cA[i] = make_float2(0.f, 0.f);
    }

    #pragma unroll
    for (int g = 0; g < 4; ++g) {
        // prefetch group g+1: records + centers
        if (g + 1 < 4) {
            #pragma unroll
            for (int i = 0; i < 8; ++i) {
                const int s = (g + 1) * 8 + i;
                const int d_in = d0 - 4 + s;
                uint3 v = make_uint3(0u, 0u, 0u);
                if (d_in >= 0 && d_in < WDIM)
                    v = *(const uint3*)(Bb + ((size_t)d_in * PLANE + base_h) * 3);
                const int d_out = d0 + s - 8;              // always in [0,192)
                const size_t cidx = (size_t)d_out * PLANE + base_h;
                const float ci = Ib[cidx];
                const float cj = Jb[cidx];
                if ((g & 1) == 0) { qB[i] = v; cB[i] = make_float2(ci, cj); }
                else              { qA[i] = v; cA[i] = make_float2(ci, cj); }
            }
        }
        // process group g
        #pragma unroll
        for (int i = 0; i < 8; ++i) {
            const int s = g * 8 + i;
            const uint3 q = ((g & 1) == 0) ? qA[i] : qB[i];
            const float f0 = bf_lo(q.x), f1 = bf_hi(q.x);
            const float f2 = bf_lo(q.y), f3 = bf_hi(q.y);
            const float f4 = bf_lo(q.z);
            const int j = s % 9;
            s0 += f0 - r0[j]; r0[j] = f0;
            s1 += f1 - r1[j]; r1[j] = f1;
            s2 += f2 - r2[j]; r2[j] = f2;
            s3 += f3 - r3[j]; r3[j] = f3;
            s4 += f4 - r4[j]; r4[j] = f4;

            if (s >= 8) {
                const float2 cc = ((g & 1) == 0) ? cA[i] : cB[i];
                const float Iu = cc.x * inv_k;
                const float Ju = cc.y * inv_k;
                const float cross = s4 - s0 * Ju - s1 * Iu + Iu * Ju * 729.0f;
                const float Ivar  = s2 - 2.0f * s0 * Iu + Iu * Iu * 729.0f;
                const float Jvar  = s3 - 2.0f * s1 * Ju + Ju * Ju * 729.0f;
                local += (cross * cross) / (Ivar * Jvar + 1e-5f);
            }
        }
    }

    __shared__ float sred[192];
    sred[t] = local;
    __syncthreads();
    if (t < 64) {
        float v = sred[t] + sred[t + 64] + sred[t + 128];
        #pragma unroll
        for (int off = 32; off; off >>= 1) v += __shfl_down(v, off);
        if (t == 0) {
            atomicAdd(out, v * (-1.0f / 14155776.0f));
        }
    }
}

extern "C" void kernel_launch(void* const* d_in, const int* in_sizes, int n_in,
                              void* d_out, int out_size, void* d_ws, size_t ws_size,
                              hipStream_t stream) {
    const float* I = (const float*)d_in[0];
    const float* J = (const float*)d_in[1];
    float* out = (float*)d_out;
    unsigned int* B = (unsigned int*)d_ws;

    zero_out_k<<<1, 1, 0, stream>>>(out);

    const size_t need2 = (size_t)2 * VOL * 12;   // 169.9 MB for both batches
    if (ws_size >= need2) {
        // merged path: both batches in one launch pair
        wh_pass<<<dim3(1536, 2), 192, 0, stream>>>(I, J, B);
        d_pass <<<dim3(1536, 2), 192, 0, stream>>>(B, I, J, out);
    } else {
        // serial fallback: one 85 MB B volume, per-batch
        for (int b = 0; b < 2; ++b) {
            const float* Ib = I + (size_t)b * VOL;
            const float* Jb = J + (size_t)b * VOL;
            wh_pass<<<dim3(1536, 1), 192, 0, stream>>>(Ib, Jb, B);
            d_pass <<<dim3(1536, 1), 192, 0, stream>>>(B, Ib, Jb, out);
        }
    }
}